// Round 1
// baseline (993.126 us; speedup 1.0000x reference)
//
#include <hip/hip_runtime.h>
#include <hip/hip_bf16.h>
#include <math.h>

// LorentzTemporalBlock — bf16 MFMA GEMMs + analytically-simplified elementwise.
// B=8,T=512,J=26,D=256,H=8,DH=32,HID=1024. R = 106496 rows (= 832*128).
// Key identities (vs reference):
//  * logmap0(expmap0(u)) == u  =>  t = LN(logmap0(x))
//  * LN(c*v) == LN(v) for c>0  =>  t = LN(xs)          [logmap0(x) = beta*xs]
//    and u2 = LN(xs + sinh(|o|)/|o| * o)               [alpha*ms, alpha>0]
//    (residual: only the 1e-5 var-eps is not scale-invariant: <=2e-4 rel)
// All transcendentals via __expf/v_rcp hardware paths; elementwise kernels
// are wave-per-row (shuffle reduce, no LDS/barriers).
// R1: k_mm epilogue restaged through LDS (16B coalesced stores, no partial-line
//     write amplification); gelu in sigmoid form with v_rcp (no f32 div seq).

#define EPSF 1e-6f
#define B_ 8
#define T_ 512
#define J_ 26
#define D_ 256
#define H_ 8
#define DH_ 32
#define HID_ 1024
#define NP1 257
#define R_ (B_*T_*J_)    // 106496

typedef float  f32x4  __attribute__((ext_vector_type(4)));
typedef short  s16x8  __attribute__((ext_vector_type(8)));

// ---------- async global->LDS 16B ----------
__device__ __forceinline__ void async16(const void* g, void* l) {
  __builtin_amdgcn_global_load_lds(
      (const __attribute__((address_space(1))) unsigned int*)g,
      (__attribute__((address_space(3))) unsigned int*)l, 16, 0, 0);
}

// ---------- wave-wide (64 lane) sum, result in all lanes ----------
__device__ __forceinline__ float wave_sum(float v) {
#pragma unroll
  for (int m = 32; m; m >>= 1) v += __shfl_xor(v, m, 64);
  return v;
}

// ---------- weight transpose+convert: W fp32 [K][N] -> Wt bf16 [N][K] ----------
__global__ __launch_bounds__(256) void k_wconv(const float* __restrict__ W,
                                               __hip_bfloat16* __restrict__ Wt,
                                               int K, int N) {
  __shared__ float tile[32][33];
  int n0 = blockIdx.x * 32, k0 = blockIdx.y * 32;
  int tx = threadIdx.x, ty = threadIdx.y;   // (32,8)
#pragma unroll
  for (int i = ty; i < 32; i += 8) tile[i][tx] = W[(size_t)(k0 + i) * N + n0 + tx];
  __syncthreads();
#pragma unroll
  for (int i = ty; i < 32; i += 8)
    Wt[(size_t)(n0 + i) * K + k0 + tx] = __float2bfloat16(tile[tx][i]);
}

// ---------- t = LN(xs)  (wave-per-row; 4 rows per block) ----------
__global__ __launch_bounds__(256) void k_t(const float* __restrict__ x,
                                           const float* __restrict__ g1,
                                           const float* __restrict__ beta1,
                                           __hip_bfloat16* __restrict__ t) {
  int r = blockIdx.x * 4 + (threadIdx.x >> 6);
  int l = threadIdx.x & 63;
  const float* xr = x + (size_t)r * NP1;
  float xs[4];
#pragma unroll
  for (int i = 0; i < 4; ++i) xs[i] = xr[1 + l + 64*i];
  float p1 = xs[0]+xs[1]+xs[2]+xs[3];
  float p2 = xs[0]*xs[0]+xs[1]*xs[1]+xs[2]*xs[2]+xs[3]*xs[3];
  float s1 = wave_sum(p1);
  float s2 = wave_sum(p2);
  float mean = s1 * (1.0f/256.0f);
  float var = s2 * (1.0f/256.0f) - mean*mean;
  float rstd = rsqrtf(var + 1e-5f);
#pragma unroll
  for (int i = 0; i < 4; ++i) {
    int c = l + 64*i;
    t[(size_t)r * D_ + c] = __float2bfloat16((xs[i]-mean)*rstd*g1[c] + beta1[c]);
  }
}

// ---------- bf16 MFMA GEMM: C = act(A @ Bt^T + bias) ----------
// A bf16 [M][K], Bt bf16 [N][K] (pre-transposed). 128x128 tile, BK=32, 4 waves.
// act: 0 none, 1 elu+1, 2 gelu(tanh). outFp32: write float else bf16.
// Epilogue: act/bias in regs -> LDS restage (XOR-swizzled) -> 16B coalesced
// global stores. Avoids 2B scattered stores (1.8x HBM write amplification).
__global__ __launch_bounds__(256) void k_mm(const __hip_bfloat16* __restrict__ A,
                                            const __hip_bfloat16* __restrict__ Bt,
                                            const float* __restrict__ bias,
                                            void* __restrict__ Cout,
                                            int M, int N, int K, int act, int outFp32) {
  __shared__ char smem[16384];
  short* As = (short*)smem;            // 128 rows x 32 k (swizzled), 8KB
  short* Bs = (short*)(smem + 8192);   // 8KB
  int tid = threadIdx.x, w = tid >> 6, l = tid & 63;
  int m0 = blockIdx.x * 128, n0 = blockIdx.y * 128;

  int offG[2], dstS[2];
#pragma unroll
  for (int p = 0; p < 2; ++p) {
    int L = (w*2 + p)*8 + (l >> 3);
    int q = (l & 7) ^ (L & 7);
    int r = 2*L + (q >> 2);
    int c = q & 3;
    offG[p] = r * K + c * 8;
    dstS[p] = (w*2 + p) * 512;
  }
  const short* Ag = (const short*)A + (size_t)m0 * K;
  const short* Bg = (const short*)Bt + (size_t)n0 * K;

  int ml = l & 15, quad = l >> 4;
  int wm = (w & 1) * 64, wn = (w >> 1) * 64;
  int aoff[4], boff[4];
#pragma unroll
  for (int i = 0; i < 4; ++i) {
    int m = wm + i*16 + ml;
    int L = m >> 1, q = (m & 1)*4 + quad;
    aoff[i] = L*64 + (q ^ (L & 7))*8;
    int n = wn + i*16 + ml;
    int L2 = n >> 1, q2 = (n & 1)*4 + quad;
    boff[i] = L2*64 + (q2 ^ (L2 & 7))*8;
  }

  f32x4 acc[4][4];
#pragma unroll
  for (int i = 0; i < 4; ++i)
#pragma unroll
    for (int j = 0; j < 4; ++j) acc[i][j] = {0.f, 0.f, 0.f, 0.f};

  for (int k0 = 0; k0 < K; k0 += 32) {
    async16(Ag + offG[0] + k0, &As[dstS[0]]);
    async16(Ag + offG[1] + k0, &As[dstS[1]]);
    async16(Bg + offG[0] + k0, &Bs[dstS[0]]);
    async16(Bg + offG[1] + k0, &Bs[dstS[1]]);
    __syncthreads();
    s16x8 af[4], bf[4];
#pragma unroll
    for (int i = 0; i < 4; ++i) af[i] = *(const s16x8*)&As[aoff[i]];
#pragma unroll
    for (int j = 0; j < 4; ++j) bf[j] = *(const s16x8*)&Bs[boff[j]];
#pragma unroll
    for (int i = 0; i < 4; ++i)
#pragma unroll
      for (int j = 0; j < 4; ++j)
        acc[i][j] = __builtin_amdgcn_mfma_f32_16x16x32_bf16(af[i], bf[j], acc[i][j], 0, 0, 0);
    __syncthreads();
  }

  // ---- epilogue: 4 passes of 32 rows through LDS ----
  // Region w holds the wave's 16x64 slab: rows m0+(w&1)*64+i*16+q, cols n0+(w>>1)*64+0..63.
  short* Cs = (short*)smem;     // bf16 path: 4 regions x 1024 shorts = 8KB
  float* Cf = (float*)smem;     // fp32 path: 4 regions x 1024 floats = 16KB
#pragma unroll
  for (int i = 0; i < 4; ++i) {
    if (i) __syncthreads();     // previous pass's reads complete
#pragma unroll
    for (int j = 0; j < 4; ++j) {
      float bj = bias[n0 + wn + j*16 + ml];
#pragma unroll
      for (int rr = 0; rr < 4; ++rr) {
        float v = acc[i][j][rr] + bj;
        if (act == 1) v = (v > 0.0f) ? v + 1.0f : __expf(v);
        else if (act == 2) {
          // gelu(tanh) in sigmoid form: v * sigmoid(1.5957691*v + 0.07135483*v^3)
          float v2 = v * v;
          float e = __expf(v * fmaf(v2, -0.0713548327f, -1.5957691216f));
          v = v * __builtin_amdgcn_rcpf(1.0f + e);   // inf-safe: e=inf -> 0
        }
        int rowL = quad*4 + rr;
        int colL = j*16 + ml;
        if (outFp32) {
          Cf[(w*1024 + rowL*64 + colL) ^ ((rowL & 15) << 2)] = v;
        } else {
          __hip_bfloat16 bv = __float2bfloat16(v);
          Cs[(w*1024 + rowL*64 + colL) ^ ((rowL & 7) << 3)] = *(short*)&bv;
        }
      }
    }
    __syncthreads();            // writes visible
    if (outFp32) {
#pragma unroll
      for (int p = 0; p < 4; ++p) {
        int idx = p*256 + tid;            // 0..1023 : 32 rows x 32 chunks(4 floats)
        int rowIdx = idx >> 5, ch = idx & 31;
        int wmb = rowIdx >> 4, q = rowIdx & 15;
        int wnb = ch >> 4, c = ch & 15;
        int fb = (((wmb + wnb*2) * 1024) + q*64 + c*4) ^ ((q & 15) << 2);
        f32x4 vv = *(const f32x4*)&Cf[fb];
        int row = m0 + wmb*64 + i*16 + q;
        int col = n0 + wnb*64 + c*4;
        *(f32x4*)&((float*)Cout)[(size_t)row * N + col] = vv;
      }
    } else {
#pragma unroll
      for (int p = 0; p < 2; ++p) {
        int idx = p*256 + tid;            // 0..511 : 32 rows x 16 chunks(8 bf16)
        int rowIdx = idx >> 4, ch = idx & 15;
        int wmb = rowIdx >> 4, q = rowIdx & 15;
        int wnb = ch >> 3, c = ch & 7;
        int sb = (((wmb + wnb*2) * 1024) + q*64 + c*8) ^ ((q & 7) << 3);
        s16x8 vv = *(const s16x8*)&Cs[sb];
        int row = m0 + wmb*64 + i*16 + q;
        int col = n0 + wnb*64 + c*8;
        *(s16x8*)&((__hip_bfloat16*)Cout)[(size_t)row * N + col] = vv;
      }
    }
  }
}

// ---------- kv + ksum per (b,j,h), fp32 accumulate from bf16 ----------
__global__ __launch_bounds__(256) void k_kv(const __hip_bfloat16* __restrict__ pk,
                                            const __hip_bfloat16* __restrict__ v,
                                            float* __restrict__ kv,
                                            float* __restrict__ ksum) {
  __shared__ float spk[8][DH_];
  __shared__ float sv[8][DH_];
  int blk = blockIdx.x;          // (b*J + j)*H + h
  int h = blk & 7;
  int bj = blk >> 3;
  int j = bj % J_;
  int b = bj / J_;
  int tid = threadIdx.x;
  int tt = tid >> 5, dl = tid & 31;
  int dd = tid & 31, k0 = tid >> 5;
  float acc[4] = {0.f, 0.f, 0.f, 0.f};
  float ks = 0.f;
  for (int t0 = 0; t0 < T_; t0 += 8) {
    size_t row = (size_t)(b * T_ + t0 + tt) * J_ + j;
    spk[tt][dl] = __bfloat162float(pk[row * D_ + h * DH_ + dl]);
    sv[tt][dl]  = __bfloat162float(v [row * D_ + h * DH_ + dl]);
    __syncthreads();
#pragma unroll
    for (int q = 0; q < 8; ++q) {
      float vv = sv[q][dd];
#pragma unroll
      for (int m = 0; m < 4; ++m)
        acc[m] = fmaf(spk[q][k0 + (m << 3)], vv, acc[m]);
    }
    if (tid < 32) {
#pragma unroll
      for (int q = 0; q < 8; ++q) ks += spk[q][tid];
    }
    __syncthreads();
  }
#pragma unroll
  for (int m = 0; m < 4; ++m)
    kv[(size_t)blk * (DH_*DH_) + (size_t)(k0 + (m << 3)) * DH_ + dd] = acc[m];
  if (tid < 32) ksum[(size_t)blk * DH_ + tid] = ks;
}

// ---------- attn = (pq @ kv) / (pq @ ksum + eps) -> bf16 ----------
// grid (T/32, B*J). kv column cached in registers (loaded once per block);
// pq rows staged fp32 in LDS (stride 264: 16B-aligned rows + bank rotation).
__global__ __launch_bounds__(256) void k_attn(const __hip_bfloat16* __restrict__ pq,
                                              const float* __restrict__ kv,
                                              const float* __restrict__ ksum,
                                              __hip_bfloat16* __restrict__ attn) {
  __shared__ float psf[32][264];
  __shared__ float dens[32][8];
  int bj = blockIdx.y;           // b*J + j
  int b = bj / J_, j = bj % J_;
  int t0 = blockIdx.x * 32;
  int tid = threadIdx.x, w = tid >> 6, l = tid & 63;
  int h = w*2 + (l >> 5), dd = l & 31;

  const float* kvp = kv + ((size_t)bj * 8 + h) * (DH_*DH_);
  float kvreg[32];
#pragma unroll
  for (int k = 0; k < 32; ++k) kvreg[k] = kvp[k*32 + dd];

  // stage 32 pq rows as fp32
  for (int tr = 0; tr < 32; ++tr) {
    int g = (b * T_ + t0 + tr) * J_ + j;
    psf[tr][tid] = __bfloat162float(pq[(size_t)g * D_ + tid]);
  }
  __syncthreads();

  // dens[tr][h] = dot(pq_row[h], ksum[h])  (one per thread)
  {
    int tr = tid & 31, hh = tid >> 5;
    const float* ksp = ksum + ((size_t)bj * 8 + hh) * DH_;
    float dsum = 0.f;
#pragma unroll
    for (int k = 0; k < 32; ++k) dsum = fmaf(psf[tr][hh*32 + k], ksp[k], dsum);
    dens[tr][hh] = dsum;
  }
  __syncthreads();

  for (int tr = 0; tr < 32; ++tr) {
    const float* pr = &psf[tr][h*32];
    float num = 0.f;
#pragma unroll
    for (int k = 0; k < 32; ++k) num = fmaf(pr[k], kvreg[k], num);
    int g = (b * T_ + t0 + tr) * J_ + j;
    float rden = __builtin_amdgcn_rcpf(dens[tr][h] + EPSF);
    attn[(size_t)g * D_ + tid] = __float2bfloat16(num * rden);
  }
}

// ---------- u2 = LN(xs + sinh(|o|)/|o| * o)  (wave-per-row) ----------
__global__ __launch_bounds__(256) void k_u2(const __hip_bfloat16* __restrict__ o,
                                            const float* __restrict__ x,
                                            const float* __restrict__ g2,
                                            const float* __restrict__ beta2,
                                            __hip_bfloat16* __restrict__ u2) {
  int r = blockIdx.x * 4 + (threadIdx.x >> 6);
  int l = threadIdx.x & 63;
  const float* xr = x + (size_t)r * NP1;
  float ov[4], xs[4];
#pragma unroll
  for (int i = 0; i < 4; ++i) {
    ov[i] = __bfloat162float(o[(size_t)r * D_ + l + 64*i]);
    xs[i] = xr[1 + l + 64*i];
  }
  float p2 = ov[0]*ov[0]+ov[1]*ov[1]+ov[2]*ov[2]+ov[3]*ov[3];
  float s2o = wave_sum(p2);
  float no = fmaxf(sqrtf(s2o), EPSF);
  float e = __expf(no);
  float c = (e - 1.0f/e) * 0.5f / no;      // sinh(no)/no
  float mi[4];
#pragma unroll
  for (int i = 0; i < 4; ++i) mi[i] = xs[i] + c * ov[i];
  float q1 = mi[0]+mi[1]+mi[2]+mi[3];
  float q2 = mi[0]*mi[0]+mi[1]*mi[1]+mi[2]*mi[2]+mi[3]*mi[3];
  float s1 = wave_sum(q1);
  float s2 = wave_sum(q2);
  float mean = s1 * (1.0f/256.0f);
  float var = s2 * (1.0f/256.0f) - mean*mean;
  float rstd = rsqrtf(var + 1e-5f);
#pragma unroll
  for (int i = 0; i < 4; ++i) {
    int cc = l + 64*i;
    u2[(size_t)r * D_ + cc] = __float2bfloat16((mi[i]-mean)*rstd*g2[cc] + beta2[cc]);
  }
}

// ---------- out = expmap0(f), f fp32  (wave-per-row) ----------
__global__ __launch_bounds__(256) void k_out(const float* __restrict__ f,
                                             float* __restrict__ out) {
  int r = blockIdx.x * 4 + (threadIdx.x >> 6);
  int l = threadIdx.x & 63;
  const float* fr = f + (size_t)r * D_;
  float fv[4];
#pragma unroll
  for (int i = 0; i < 4; ++i) fv[i] = fr[l + 64*i];
  float p2 = fv[0]*fv[0]+fv[1]*fv[1]+fv[2]*fv[2]+fv[3]*fv[3];
  float s2 = wave_sum(p2);
  float n = fmaxf(sqrtf(s2), EPSF);
  float e = __expf(n);
  float ie = 1.0f / e;
  float sh = (e - ie) * 0.5f;
  float ch = (e + ie) * 0.5f;
  float s = sh / n;
  float* orow = out + (size_t)r * NP1;
  if (l == 0) orow[0] = ch;
#pragma unroll
  for (int i = 0; i < 4; ++i) orow[1 + l + 64*i] = s * fv[i];
}

extern "C" void kernel_launch(void* const* d_in, const int* in_sizes, int n_in,
                              void* d_out, int out_size, void* d_ws, size_t ws_size,
                              hipStream_t stream) {
  const float* x     = (const float*)d_in[0];
  const float* g1    = (const float*)d_in[1];
  const float* beta1 = (const float*)d_in[2];
  const float* Wq    = (const float*)d_in[3];
  const float* Wk    = (const float*)d_in[4];
  const float* Wv    = (const float*)d_in[5];
  const float* Wo    = (const float*)d_in[6];
  const float* bq    = (const float*)d_in[7];
  const float* bk    = (const float*)d_in[8];
  const float* bv    = (const float*)d_in[9];
  const float* bo    = (const float*)d_in[10];
  const float* g2    = (const float*)d_in[11];
  const float* beta2 = (const float*)d_in[12];
  const float* W1    = (const float*)d_in[13];
  const float* bf1   = (const float*)d_in[14];
  const float* W2    = (const float*)d_in[15];
  const float* bf2   = (const float*)d_in[16];
  float* out = (float*)d_out;
  char* ws = (char*)d_ws;

  // ---- workspace layout (bytes) ----
  size_t off = 0;
  __hip_bfloat16* wqT = (__hip_bfloat16*)(ws + off); off += (size_t)D_*D_*2;
  __hip_bfloat16* wkT = (__hip_bfloat16*)(ws + off); off += (size_t)D_*D_*2;
  __hip_bfloat16* wvT = (__hip_bfloat16*)(ws + off); off += (size_t)D_*D_*2;
  __hip_bfloat16* woT = (__hip_bfloat16*)(ws + off); off += (size_t)D_*D_*2;
  __hip_bfloat16* w1T = (__hip_bfloat16*)(ws + off); off += (size_t)HID_*D_*2;
  __hip_bfloat16* w2T = (__hip_bfloat16*)(ws + off); off += (size_t)D_*HID_*2;
  float* kvb = (float*)(ws + off); off += (size_t)(B_*J_*H_)*(DH_*DH_)*4;
  float* ksb = (float*)(ws + off); off += (size_t)(B_*J_*H_)*DH_*4;
  off = (off + 255) & ~(size_t)255;
  __hip_bfloat16* tb = (__hip_bfloat16*)(ws + off); off += (size_t)R_*D_*2;
  __hip_bfloat16* qb = (__hip_bfloat16*)(ws + off); off += (size_t)R_*D_*2;
  __hip_bfloat16* kb = (__hip_bfloat16*)(ws + off); off += (size_t)R_*D_*2;
  __hip_bfloat16* vb = (__hip_bfloat16*)(ws + off); off += (size_t)R_*D_*2;
  __hip_bfloat16* hid = (__hip_bfloat16*)(ws + off); off += (size_t)(R_/2)*HID_*2;
  float* fbuf = (float*)qb;   // fp32 R*256 aliases qb+kb (both consumed by then)

  dim3 tconv(32, 8);
  k_wconv<<<dim3(D_/32,  D_/32),  tconv, 0, stream>>>(Wq, wqT, D_,  D_);
  k_wconv<<<dim3(D_/32,  D_/32),  tconv, 0, stream>>>(Wk, wkT, D_,  D_);
  k_wconv<<<dim3(D_/32,  D_/32),  tconv, 0, stream>>>(Wv, wvT, D_,  D_);
  k_wconv<<<dim3(D_/32,  D_/32),  tconv, 0, stream>>>(Wo, woT, D_,  D_);
  k_wconv<<<dim3(HID_/32, D_/32), tconv, 0, stream>>>(W1, w1T, D_,  HID_);
  k_wconv<<<dim3(D_/32, HID_/32), tconv, 0, stream>>>(W2, w2T, HID_, D_);

  k_t<<<R_/4, 256, 0, stream>>>(x, g1, beta1, tb);

  dim3 gqkv(R_/128, D_/128);                 // (832, 2)
  k_mm<<<gqkv, 256, 0, stream>>>(tb, wqT, bq, qb, R_, D_, D_, 1, 0);
  k_mm<<<gqkv, 256, 0, stream>>>(tb, wkT, bk, kb, R_, D_, D_, 1, 0);
  k_mm<<<gqkv, 256, 0, stream>>>(tb, wvT, bv, vb, R_, D_, D_, 0, 0);

  k_kv<<<B_*J_*H_, 256, 0, stream>>>(kb, vb, kvb, ksb);
  k_attn<<<dim3(T_/32, B_*J_), 256, 0, stream>>>(qb, kvb, ksb, kb);   // attn -> kb

  k_mm<<<gqkv, 256, 0, stream>>>(kb, woT, bo, vb, R_, D_, D_, 0, 0);  // o -> vb
  k_u2<<<R_/4, 256, 0, stream>>>(vb, x, g2, beta2, tb);               // u2 -> tb

  const int Rc = R_ / 2;                     // 53248 rows per MLP chunk
  for (int c = 0; c < 2; ++c) {
    k_mm<<<dim3(Rc/128, HID_/128), 256, 0, stream>>>(
        tb + (size_t)c * Rc * D_, w1T, bf1, hid, Rc, HID_, D_, 2, 0);
    k_mm<<<dim3(Rc/128, D_/128), 256, 0, stream>>>(
        hid, w2T, bf2, fbuf + (size_t)c * Rc * D_, Rc, D_, HID_, 0, 1);
  }

  k_out<<<R_/4, 256, 0, stream>>>(fbuf, out);
}

// Round 2
// 962.996 us; speedup vs baseline: 1.0313x; 1.0313x over previous
//
#include <hip/hip_runtime.h>
#include <hip/hip_bf16.h>
#include <math.h>

// LorentzTemporalBlock — bf16 MFMA GEMMs + analytically-simplified elementwise.
// B=8,T=512,J=26,D=256,H=8,DH=32,HID=1024. R = 106496 rows (= 832*128).
// Key identities (vs reference):
//  * logmap0(expmap0(u)) == u  =>  t = LN(logmap0(x))
//  * LN(c*v) == LN(v) for c>0  =>  t = LN(xs)          [logmap0(x) = beta*xs]
//    and u2 = LN(xs + sinh(|o|)/|o| * o)               [alpha*ms, alpha>0]
//    (residual: only the 1e-5 var-eps is not scale-invariant: <=2e-4 rel)
// R1: k_mm epilogue restaged through LDS (16B coalesced stores; WRITE_SIZE now
//     exactly ideal); gelu in sigmoid form with v_rcp.
// R2: k_mm K-loop double-buffered (stage next tile BEFORE compute, ONE barrier
//     per K-step — load latency hides under ds_read+MFMA); grid swapped to
//     N-fast so co-resident blocks share the A-tile (L2/L3 locality).

#define EPSF 1e-6f
#define B_ 8
#define T_ 512
#define J_ 26
#define D_ 256
#define H_ 8
#define DH_ 32
#define HID_ 1024
#define NP1 257
#define R_ (B_*T_*J_)    // 106496

typedef float  f32x4  __attribute__((ext_vector_type(4)));
typedef short  s16x8  __attribute__((ext_vector_type(8)));

// ---------- async global->LDS 16B ----------
__device__ __forceinline__ void async16(const void* g, void* l) {
  __builtin_amdgcn_global_load_lds(
      (const __attribute__((address_space(1))) unsigned int*)g,
      (__attribute__((address_space(3))) unsigned int*)l, 16, 0, 0);
}

// ---------- wave-wide (64 lane) sum, result in all lanes ----------
__device__ __forceinline__ float wave_sum(float v) {
#pragma unroll
  for (int m = 32; m; m >>= 1) v += __shfl_xor(v, m, 64);
  return v;
}

// ---------- weight transpose+convert: W fp32 [K][N] -> Wt bf16 [N][K] ----------
__global__ __launch_bounds__(256) void k_wconv(const float* __restrict__ W,
                                               __hip_bfloat16* __restrict__ Wt,
                                               int K, int N) {
  __shared__ float tile[32][33];
  int n0 = blockIdx.x * 32, k0 = blockIdx.y * 32;
  int tx = threadIdx.x, ty = threadIdx.y;   // (32,8)
#pragma unroll
  for (int i = ty; i < 32; i += 8) tile[i][tx] = W[(size_t)(k0 + i) * N + n0 + tx];
  __syncthreads();
#pragma unroll
  for (int i = ty; i < 32; i += 8)
    Wt[(size_t)(n0 + i) * K + k0 + tx] = __float2bfloat16(tile[tx][i]);
}

// ---------- t = LN(xs)  (wave-per-row; 4 rows per block) ----------
__global__ __launch_bounds__(256) void k_t(const float* __restrict__ x,
                                           const float* __restrict__ g1,
                                           const float* __restrict__ beta1,
                                           __hip_bfloat16* __restrict__ t) {
  int r = blockIdx.x * 4 + (threadIdx.x >> 6);
  int l = threadIdx.x & 63;
  const float* xr = x + (size_t)r * NP1;
  float xs[4];
#pragma unroll
  for (int i = 0; i < 4; ++i) xs[i] = xr[1 + l + 64*i];
  float p1 = xs[0]+xs[1]+xs[2]+xs[3];
  float p2 = xs[0]*xs[0]+xs[1]*xs[1]+xs[2]*xs[2]+xs[3]*xs[3];
  float s1 = wave_sum(p1);
  float s2 = wave_sum(p2);
  float mean = s1 * (1.0f/256.0f);
  float var = s2 * (1.0f/256.0f) - mean*mean;
  float rstd = rsqrtf(var + 1e-5f);
#pragma unroll
  for (int i = 0; i < 4; ++i) {
    int c = l + 64*i;
    t[(size_t)r * D_ + c] = __float2bfloat16((xs[i]-mean)*rstd*g1[c] + beta1[c]);
  }
}

// ---------- bf16 MFMA GEMM: C = act(A @ Bt^T + bias) ----------
// A bf16 [M][K], Bt bf16 [N][K] (pre-transposed). 128x128 tile, BK=32, 4 waves.
// Grid: (N/128, M/128) — N-fast so co-resident blocks share the A-tile.
// K-loop: double-buffered LDS (stage k+1 before computing k; one barrier/step).
// act: 0 none, 1 elu+1, 2 gelu(tanh). outFp32: write float else bf16.
// Epilogue: act/bias in regs -> LDS restage (XOR-swizzled) -> 16B coalesced
// global stores.
__global__ __launch_bounds__(256) void k_mm(const __hip_bfloat16* __restrict__ A,
                                            const __hip_bfloat16* __restrict__ Bt,
                                            const float* __restrict__ bias,
                                            void* __restrict__ Cout,
                                            int M, int N, int K, int act, int outFp32) {
  __shared__ char smem[32768];
  short* As = (short*)smem;             // 2 bufs x 4096 shorts (8KB each)
  short* Bs = (short*)(smem + 16384);   // 2 bufs x 4096 shorts
  int tid = threadIdx.x, w = tid >> 6, l = tid & 63;
  int n0 = blockIdx.x * 128, m0 = blockIdx.y * 128;

  int offG[2], dstS[2];
#pragma unroll
  for (int p = 0; p < 2; ++p) {
    int L = (w*2 + p)*8 + (l >> 3);
    int q = (l & 7) ^ (L & 7);
    int r = 2*L + (q >> 2);
    int c = q & 3;
    offG[p] = r * K + c * 8;
    dstS[p] = (w*2 + p) * 512;
  }
  const short* Ag = (const short*)A + (size_t)m0 * K;
  const short* Bg = (const short*)Bt + (size_t)n0 * K;

  int ml = l & 15, quad = l >> 4;
  int wm = (w & 1) * 64, wn = (w >> 1) * 64;
  int aoff[4], boff[4];
#pragma unroll
  for (int i = 0; i < 4; ++i) {
    int m = wm + i*16 + ml;
    int L = m >> 1, q = (m & 1)*4 + quad;
    aoff[i] = L*64 + (q ^ (L & 7))*8;
    int n = wn + i*16 + ml;
    int L2 = n >> 1, q2 = (n & 1)*4 + quad;
    boff[i] = L2*64 + (q2 ^ (L2 & 7))*8;
  }

  f32x4 acc[4][4];
#pragma unroll
  for (int i = 0; i < 4; ++i)
#pragma unroll
    for (int j = 0; j < 4; ++j) acc[i][j] = {0.f, 0.f, 0.f, 0.f};

  auto STAGE = [&](int bo, int k0) {
    async16(Ag + offG[0] + k0, &As[bo + dstS[0]]);
    async16(Ag + offG[1] + k0, &As[bo + dstS[1]]);
    async16(Bg + offG[0] + k0, &Bs[bo + dstS[0]]);
    async16(Bg + offG[1] + k0, &Bs[bo + dstS[1]]);
  };
  auto COMPUTE = [&](int bo) {
    s16x8 af[4], bf[4];
#pragma unroll
    for (int i = 0; i < 4; ++i) af[i] = *(const s16x8*)&As[bo + aoff[i]];
#pragma unroll
    for (int j = 0; j < 4; ++j) bf[j] = *(const s16x8*)&Bs[bo + boff[j]];
#pragma unroll
    for (int i = 0; i < 4; ++i)
#pragma unroll
      for (int j = 0; j < 4; ++j)
        acc[i][j] = __builtin_amdgcn_mfma_f32_16x16x32_bf16(af[i], bf[j], acc[i][j], 0, 0, 0);
  };

  // prologue: tile 0 into buf0 (barrier drains vmcnt before first reads)
  STAGE(0, 0);
  __syncthreads();
  int KT = K >> 5;                       // 8 or 32 (always even)
  for (int kt = 0; kt < KT; kt += 2) {
    STAGE(4096, (kt + 1) << 5);          // prefetch next tile -> buf1
    COMPUTE(0);                          //   latency hides under ds_read+MFMA
    __syncthreads();                     // buf1 ready; buf0 reads retired
    if (kt + 2 < KT) STAGE(0, (kt + 2) << 5);
    COMPUTE(4096);
    __syncthreads();
  }

  // ---- epilogue: 4 passes of 32 rows through LDS ----
  // Region w holds the wave's 16x64 slab: rows m0+(w&1)*64+i*16+q, cols n0+(w>>1)*64+0..63.
  short* Cs = (short*)smem;     // bf16 path: 4 regions x 1024 shorts = 8KB
  float* Cf = (float*)smem;     // fp32 path: 4 regions x 1024 floats = 16KB
#pragma unroll
  for (int i = 0; i < 4; ++i) {
    if (i) __syncthreads();     // previous pass's reads complete
#pragma unroll
    for (int j = 0; j < 4; ++j) {
      float bj = bias[n0 + wn + j*16 + ml];
#pragma unroll
      for (int rr = 0; rr < 4; ++rr) {
        float v = acc[i][j][rr] + bj;
        if (act == 1) v = (v > 0.0f) ? v + 1.0f : __expf(v);
        else if (act == 2) {
          // gelu(tanh) in sigmoid form: v * sigmoid(1.5957691*v + 0.07135483*v^3)
          float v2 = v * v;
          float e = __expf(v * fmaf(v2, -0.0713548327f, -1.5957691216f));
          v = v * __builtin_amdgcn_rcpf(1.0f + e);   // inf-safe: e=inf -> 0
        }
        int rowL = quad*4 + rr;
        int colL = j*16 + ml;
        if (outFp32) {
          Cf[(w*1024 + rowL*64 + colL) ^ ((rowL & 15) << 2)] = v;
        } else {
          __hip_bfloat16 bv = __float2bfloat16(v);
          Cs[(w*1024 + rowL*64 + colL) ^ ((rowL & 7) << 3)] = *(short*)&bv;
        }
      }
    }
    __syncthreads();            // writes visible
    if (outFp32) {
#pragma unroll
      for (int p = 0; p < 4; ++p) {
        int idx = p*256 + tid;            // 0..1023 : 32 rows x 32 chunks(4 floats)
        int rowIdx = idx >> 5, ch = idx & 31;
        int wmb = rowIdx >> 4, q = rowIdx & 15;
        int wnb = ch >> 4, c = ch & 15;
        int fb = (((wmb + wnb*2) * 1024) + q*64 + c*4) ^ ((q & 15) << 2);
        f32x4 vv = *(const f32x4*)&Cf[fb];
        int row = m0 + wmb*64 + i*16 + q;
        int col = n0 + wnb*64 + c*4;
        *(f32x4*)&((float*)Cout)[(size_t)row * N + col] = vv;
      }
    } else {
#pragma unroll
      for (int p = 0; p < 2; ++p) {
        int idx = p*256 + tid;            // 0..511 : 32 rows x 16 chunks(8 bf16)
        int rowIdx = idx >> 4, ch = idx & 15;
        int wmb = rowIdx >> 4, q = rowIdx & 15;
        int wnb = ch >> 3, c = ch & 7;
        int sb = (((wmb + wnb*2) * 1024) + q*64 + c*8) ^ ((q & 7) << 3);
        s16x8 vv = *(const s16x8*)&Cs[sb];
        int row = m0 + wmb*64 + i*16 + q;
        int col = n0 + wnb*64 + c*8;
        *(s16x8*)&((__hip_bfloat16*)Cout)[(size_t)row * N + col] = vv;
      }
    }
  }
}

// ---------- kv + ksum per (b,j,h), fp32 accumulate from bf16 ----------
__global__ __launch_bounds__(256) void k_kv(const __hip_bfloat16* __restrict__ pk,
                                            const __hip_bfloat16* __restrict__ v,
                                            float* __restrict__ kv,
                                            float* __restrict__ ksum) {
  __shared__ float spk[8][DH_];
  __shared__ float sv[8][DH_];
  int blk = blockIdx.x;          // (b*J + j)*H + h
  int h = blk & 7;
  int bj = blk >> 3;
  int j = bj % J_;
  int b = bj / J_;
  int tid = threadIdx.x;
  int tt = tid >> 5, dl = tid & 31;
  int dd = tid & 31, k0 = tid >> 5;
  float acc[4] = {0.f, 0.f, 0.f, 0.f};
  float ks = 0.f;
  for (int t0 = 0; t0 < T_; t0 += 8) {
    size_t row = (size_t)(b * T_ + t0 + tt) * J_ + j;
    spk[tt][dl] = __bfloat162float(pk[row * D_ + h * DH_ + dl]);
    sv[tt][dl]  = __bfloat162float(v [row * D_ + h * DH_ + dl]);
    __syncthreads();
#pragma unroll
    for (int q = 0; q < 8; ++q) {
      float vv = sv[q][dd];
#pragma unroll
      for (int m = 0; m < 4; ++m)
        acc[m] = fmaf(spk[q][k0 + (m << 3)], vv, acc[m]);
    }
    if (tid < 32) {
#pragma unroll
      for (int q = 0; q < 8; ++q) ks += spk[q][tid];
    }
    __syncthreads();
  }
#pragma unroll
  for (int m = 0; m < 4; ++m)
    kv[(size_t)blk * (DH_*DH_) + (size_t)(k0 + (m << 3)) * DH_ + dd] = acc[m];
  if (tid < 32) ksum[(size_t)blk * DH_ + tid] = ks;
}

// ---------- attn = (pq @ kv) / (pq @ ksum + eps) -> bf16 ----------
// grid (T/32, B*J). kv column cached in registers (loaded once per block);
// pq rows staged fp32 in LDS (stride 264: 16B-aligned rows + bank rotation).
__global__ __launch_bounds__(256) void k_attn(const __hip_bfloat16* __restrict__ pq,
                                              const float* __restrict__ kv,
                                              const float* __restrict__ ksum,
                                              __hip_bfloat16* __restrict__ attn) {
  __shared__ float psf[32][264];
  __shared__ float dens[32][8];
  int bj = blockIdx.y;           // b*J + j
  int b = bj / J_, j = bj % J_;
  int t0 = blockIdx.x * 32;
  int tid = threadIdx.x, w = tid >> 6, l = tid & 63;
  int h = w*2 + (l >> 5), dd = l & 31;

  const float* kvp = kv + ((size_t)bj * 8 + h) * (DH_*DH_);
  float kvreg[32];
#pragma unroll
  for (int k = 0; k < 32; ++k) kvreg[k] = kvp[k*32 + dd];

  // stage 32 pq rows as fp32
  for (int tr = 0; tr < 32; ++tr) {
    int g = (b * T_ + t0 + tr) * J_ + j;
    psf[tr][tid] = __bfloat162float(pq[(size_t)g * D_ + tid]);
  }
  __syncthreads();

  // dens[tr][h] = dot(pq_row[h], ksum[h])  (one per thread)
  {
    int tr = tid & 31, hh = tid >> 5;
    const float* ksp = ksum + ((size_t)bj * 8 + hh) * DH_;
    float dsum = 0.f;
#pragma unroll
    for (int k = 0; k < 32; ++k) dsum = fmaf(psf[tr][hh*32 + k], ksp[k], dsum);
    dens[tr][hh] = dsum;
  }
  __syncthreads();

  for (int tr = 0; tr < 32; ++tr) {
    const float* pr = &psf[tr][h*32];
    float num = 0.f;
#pragma unroll
    for (int k = 0; k < 32; ++k) num = fmaf(pr[k], kvreg[k], num);
    int g = (b * T_ + t0 + tr) * J_ + j;
    float rden = __builtin_amdgcn_rcpf(dens[tr][h] + EPSF);
    attn[(size_t)g * D_ + tid] = __float2bfloat16(num * rden);
  }
}

// ---------- u2 = LN(xs + sinh(|o|)/|o| * o)  (wave-per-row) ----------
__global__ __launch_bounds__(256) void k_u2(const __hip_bfloat16* __restrict__ o,
                                            const float* __restrict__ x,
                                            const float* __restrict__ g2,
                                            const float* __restrict__ beta2,
                                            __hip_bfloat16* __restrict__ u2) {
  int r = blockIdx.x * 4 + (threadIdx.x >> 6);
  int l = threadIdx.x & 63;
  const float* xr = x + (size_t)r * NP1;
  float ov[4], xs[4];
#pragma unroll
  for (int i = 0; i < 4; ++i) {
    ov[i] = __bfloat162float(o[(size_t)r * D_ + l + 64*i]);
    xs[i] = xr[1 + l + 64*i];
  }
  float p2 = ov[0]*ov[0]+ov[1]*ov[1]+ov[2]*ov[2]+ov[3]*ov[3];
  float s2o = wave_sum(p2);
  float no = fmaxf(sqrtf(s2o), EPSF);
  float e = __expf(no);
  float c = (e - 1.0f/e) * 0.5f / no;      // sinh(no)/no
  float mi[4];
#pragma unroll
  for (int i = 0; i < 4; ++i) mi[i] = xs[i] + c * ov[i];
  float q1 = mi[0]+mi[1]+mi[2]+mi[3];
  float q2 = mi[0]*mi[0]+mi[1]*mi[1]+mi[2]*mi[2]+mi[3]*mi[3];
  float s1 = wave_sum(q1);
  float s2 = wave_sum(q2);
  float mean = s1 * (1.0f/256.0f);
  float var = s2 * (1.0f/256.0f) - mean*mean;
  float rstd = rsqrtf(var + 1e-5f);
#pragma unroll
  for (int i = 0; i < 4; ++i) {
    int cc = l + 64*i;
    u2[(size_t)r * D_ + cc] = __float2bfloat16((mi[i]-mean)*rstd*g2[cc] + beta2[cc]);
  }
}

// ---------- out = expmap0(f), f fp32  (wave-per-row) ----------
__global__ __launch_bounds__(256) void k_out(const float* __restrict__ f,
                                             float* __restrict__ out) {
  int r = blockIdx.x * 4 + (threadIdx.x >> 6);
  int l = threadIdx.x & 63;
  const float* fr = f + (size_t)r * D_;
  float fv[4];
#pragma unroll
  for (int i = 0; i < 4; ++i) fv[i] = fr[l + 64*i];
  float p2 = fv[0]*fv[0]+fv[1]*fv[1]+fv[2]*fv[2]+fv[3]*fv[3];
  float s2 = wave_sum(p2);
  float n = fmaxf(sqrtf(s2), EPSF);
  float e = __expf(n);
  float ie = 1.0f / e;
  float sh = (e - ie) * 0.5f;
  float ch = (e + ie) * 0.5f;
  float s = sh / n;
  float* orow = out + (size_t)r * NP1;
  if (l == 0) orow[0] = ch;
#pragma unroll
  for (int i = 0; i < 4; ++i) orow[1 + l + 64*i] = s * fv[i];
}

extern "C" void kernel_launch(void* const* d_in, const int* in_sizes, int n_in,
                              void* d_out, int out_size, void* d_ws, size_t ws_size,
                              hipStream_t stream) {
  const float* x     = (const float*)d_in[0];
  const float* g1    = (const float*)d_in[1];
  const float* beta1 = (const float*)d_in[2];
  const float* Wq    = (const float*)d_in[3];
  const float* Wk    = (const float*)d_in[4];
  const float* Wv    = (const float*)d_in[5];
  const float* Wo    = (const float*)d_in[6];
  const float* bq    = (const float*)d_in[7];
  const float* bk    = (const float*)d_in[8];
  const float* bv    = (const float*)d_in[9];
  const float* bo    = (const float*)d_in[10];
  const float* g2    = (const float*)d_in[11];
  const float* beta2 = (const float*)d_in[12];
  const float* W1    = (const float*)d_in[13];
  const float* bf1   = (const float*)d_in[14];
  const float* W2    = (const float*)d_in[15];
  const float* bf2   = (const float*)d_in[16];
  float* out = (float*)d_out;
  char* ws = (char*)d_ws;

  // ---- workspace layout (bytes) ----
  size_t off = 0;
  __hip_bfloat16* wqT = (__hip_bfloat16*)(ws + off); off += (size_t)D_*D_*2;
  __hip_bfloat16* wkT = (__hip_bfloat16*)(ws + off); off += (size_t)D_*D_*2;
  __hip_bfloat16* wvT = (__hip_bfloat16*)(ws + off); off += (size_t)D_*D_*2;
  __hip_bfloat16* woT = (__hip_bfloat16*)(ws + off); off += (size_t)D_*D_*2;
  __hip_bfloat16* w1T = (__hip_bfloat16*)(ws + off); off += (size_t)HID_*D_*2;
  __hip_bfloat16* w2T = (__hip_bfloat16*)(ws + off); off += (size_t)D_*HID_*2;
  float* kvb = (float*)(ws + off); off += (size_t)(B_*J_*H_)*(DH_*DH_)*4;
  float* ksb = (float*)(ws + off); off += (size_t)(B_*J_*H_)*DH_*4;
  off = (off + 255) & ~(size_t)255;
  __hip_bfloat16* tb = (__hip_bfloat16*)(ws + off); off += (size_t)R_*D_*2;
  __hip_bfloat16* qb = (__hip_bfloat16*)(ws + off); off += (size_t)R_*D_*2;
  __hip_bfloat16* kb = (__hip_bfloat16*)(ws + off); off += (size_t)R_*D_*2;
  __hip_bfloat16* vb = (__hip_bfloat16*)(ws + off); off += (size_t)R_*D_*2;
  __hip_bfloat16* hid = (__hip_bfloat16*)(ws + off); off += (size_t)(R_/2)*HID_*2;
  float* fbuf = (float*)qb;   // fp32 R*256 aliases qb+kb (both consumed by then)

  dim3 tconv(32, 8);
  k_wconv<<<dim3(D_/32,  D_/32),  tconv, 0, stream>>>(Wq, wqT, D_,  D_);
  k_wconv<<<dim3(D_/32,  D_/32),  tconv, 0, stream>>>(Wk, wkT, D_,  D_);
  k_wconv<<<dim3(D_/32,  D_/32),  tconv, 0, stream>>>(Wv, wvT, D_,  D_);
  k_wconv<<<dim3(D_/32,  D_/32),  tconv, 0, stream>>>(Wo, woT, D_,  D_);
  k_wconv<<<dim3(HID_/32, D_/32), tconv, 0, stream>>>(W1, w1T, D_,  HID_);
  k_wconv<<<dim3(D_/32, HID_/32), tconv, 0, stream>>>(W2, w2T, HID_, D_);

  k_t<<<R_/4, 256, 0, stream>>>(x, g1, beta1, tb);

  dim3 gqkv(D_/128, R_/128);                 // (2, 832) — N-fast
  k_mm<<<gqkv, 256, 0, stream>>>(tb, wqT, bq, qb, R_, D_, D_, 1, 0);
  k_mm<<<gqkv, 256, 0, stream>>>(tb, wkT, bk, kb, R_, D_, D_, 1, 0);
  k_mm<<<gqkv, 256, 0, stream>>>(tb, wvT, bv, vb, R_, D_, D_, 0, 0);

  k_kv<<<B_*J_*H_, 256, 0, stream>>>(kb, vb, kvb, ksb);
  k_attn<<<dim3(T_/32, B_*J_), 256, 0, stream>>>(qb, kvb, ksb, kb);   // attn -> kb

  k_mm<<<gqkv, 256, 0, stream>>>(kb, woT, bo, vb, R_, D_, D_, 0, 0);  // o -> vb
  k_u2<<<R_/4, 256, 0, stream>>>(vb, x, g2, beta2, tb);               // u2 -> tb

  const int Rc = R_ / 2;                     // 53248 rows per MLP chunk
  for (int c = 0; c < 2; ++c) {
    k_mm<<<dim3(HID_/128, Rc/128), 256, 0, stream>>>(
        tb + (size_t)c * Rc * D_, w1T, bf1, hid, Rc, HID_, D_, 2, 0);
    k_mm<<<dim3(D_/128, Rc/128), 256, 0, stream>>>(
        hid, w2T, bf2, fbuf + (size_t)c * Rc * D_, Rc, D_, HID_, 0, 1);
  }

  k_out<<<R_/4, 256, 0, stream>>>(fbuf, out);
}

// Round 3
// 802.396 us; speedup vs baseline: 1.2377x; 1.2002x over previous
//
#include <hip/hip_runtime.h>
#include <hip/hip_bf16.h>
#include <math.h>

// LorentzTemporalBlock — bf16 MFMA GEMMs + analytically-simplified elementwise.
// B=8,T=512,J=26,D=256,H=8,DH=32,HID=1024. R = 106496 rows (= 416*256).
// Identities: t = LN(xs); u2 = LN(xs + sinh(|o|)/|o| * o)  (LN scale-invariance).
// R1: coalesced epilogue stores (WRITE_SIZE exactly ideal); sigmoid-form gelu.
// R2: 2-phase dbuf + N-fast grid — NULL (m97-structure ceiling at K=256).
// R3: full 8-phase 256x256 MFMA GEMM (T2 swizzle + T3/T4 counted-vmcnt
//     pipeline + T5 setprio), 8 waves, 128KB LDS, BK=64.
//     Stage rule: phase g stages half-tile g+6 (order A0,B0,A1,B1 per K-tile);
//     vmcnt(4) only at phases g%4==3; raw s_barrier (no vmcnt0 drain).
//     mfma(b,a,acc) operand swap -> lane owns 4 consecutive cols -> vector
//     epilogue stores (8B bf16 / 16B f32), f32x4 bias loads.

#define EPSF 1e-6f
#define B_ 8
#define T_ 512
#define J_ 26
#define D_ 256
#define H_ 8
#define DH_ 32
#define HID_ 1024
#define NP1 257
#define R_ (B_*T_*J_)    // 106496

typedef float  f32x4  __attribute__((ext_vector_type(4)));
typedef short  s16x8  __attribute__((ext_vector_type(8)));
typedef short  s16x4  __attribute__((ext_vector_type(4)));

// ---------- async global->LDS 16B (dst = uniform base + lane*16) ----------
__device__ __forceinline__ void async16(const void* g, void* l) {
  __builtin_amdgcn_global_load_lds(
      (const __attribute__((address_space(1))) unsigned int*)g,
      (__attribute__((address_space(3))) unsigned int*)l, 16, 0, 0);
}

// ---------- wave-wide (64 lane) sum, result in all lanes ----------
__device__ __forceinline__ float wave_sum(float v) {
#pragma unroll
  for (int m = 32; m; m >>= 1) v += __shfl_xor(v, m, 64);
  return v;
}

// ---------- weight transpose+convert: W fp32 [K][N] -> Wt bf16 [N][K] ----------
__global__ __launch_bounds__(256) void k_wconv(const float* __restrict__ W,
                                               __hip_bfloat16* __restrict__ Wt,
                                               int K, int N) {
  __shared__ float tile[32][33];
  int n0 = blockIdx.x * 32, k0 = blockIdx.y * 32;
  int tx = threadIdx.x, ty = threadIdx.y;   // (32,8)
#pragma unroll
  for (int i = ty; i < 32; i += 8) tile[i][tx] = W[(size_t)(k0 + i) * N + n0 + tx];
  __syncthreads();
#pragma unroll
  for (int i = ty; i < 32; i += 8)
    Wt[(size_t)(n0 + i) * K + k0 + tx] = __float2bfloat16(tile[tx][i]);
}

// ---------- t = LN(xs)  (wave-per-row; 4 rows per block) ----------
__global__ __launch_bounds__(256) void k_t(const float* __restrict__ x,
                                           const float* __restrict__ g1,
                                           const float* __restrict__ beta1,
                                           __hip_bfloat16* __restrict__ t) {
  int r = blockIdx.x * 4 + (threadIdx.x >> 6);
  int l = threadIdx.x & 63;
  const float* xr = x + (size_t)r * NP1;
  float xs[4];
#pragma unroll
  for (int i = 0; i < 4; ++i) xs[i] = xr[1 + l + 64*i];
  float p1 = xs[0]+xs[1]+xs[2]+xs[3];
  float p2 = xs[0]*xs[0]+xs[1]*xs[1]+xs[2]*xs[2]+xs[3]*xs[3];
  float s1 = wave_sum(p1);
  float s2 = wave_sum(p2);
  float mean = s1 * (1.0f/256.0f);
  float var = s2 * (1.0f/256.0f) - mean*mean;
  float rstd = rsqrtf(var + 1e-5f);
#pragma unroll
  for (int i = 0; i < 4; ++i) {
    int c = l + 64*i;
    t[(size_t)r * D_ + c] = __float2bfloat16((xs[i]-mean)*rstd*g1[c] + beta1[c]);
  }
}

// ---------- 256x256 8-phase bf16 MFMA GEMM: C = act(A @ Bt^T + bias) ----------
// A bf16 [M][K], Bt bf16 [N][K]. 8 waves (2Mx4N), BK=64, LDS 128KB:
//   A: [buf][half] 16KB each at 0..64KB;  B: same at 64..128KB.
//   half h of A-tile = rows h*128..h*128+127 (B: cols).
// Wave w: wr=w>>2, wc=w&3. Per-wave out 128x64: rows {mh*128+wr*64+f*16},
// cols {nh*128+wc*32+ni*16} — quadrant (mh,nh) per phase reads A-half mh,
// B-half nh only => halves free early => staging runs 6 phases ahead.
// LDS swizzle: 16B-slot index ^= (row&7), both on gload source and ds_read.
#define PHASE(BUF, MH, NH, GIDX, DO_VM) {                                      \
    s16x8 af_[4][2]; s16x8 bf_[2][2];                                          \
    const char* ab_ = lds + ((BUF)*2+(MH))*16384;                              \
    const char* bb_ = lds + 65536 + ((BUF)*2+(NH))*16384;                      \
    _Pragma("unroll") for (int f_ = 0; f_ < 4; ++f_)                           \
      _Pragma("unroll") for (int ks_ = 0; ks_ < 2; ++ks_)                      \
        af_[f_][ks_] = *(const s16x8*)(ab_ + aoffs[f_][ks_]);                  \
    _Pragma("unroll") for (int ni_ = 0; ni_ < 2; ++ni_)                        \
      _Pragma("unroll") for (int ks_ = 0; ks_ < 2; ++ks_)                      \
        bf_[ni_][ks_] = *(const s16x8*)(bb_ + boffs[ni_][ks_]);                \
    STAGE_HALF((GIDX) + 6);                                                    \
    if (DO_VM) asm volatile("s_waitcnt vmcnt(4)" ::: "memory");                \
    asm volatile("s_barrier" ::: "memory");                                    \
    __builtin_amdgcn_sched_barrier(0);                                         \
    __builtin_amdgcn_s_setprio(1);                                             \
    _Pragma("unroll") for (int ks_ = 0; ks_ < 2; ++ks_)                        \
      _Pragma("unroll") for (int f_ = 0; f_ < 4; ++f_)                         \
        _Pragma("unroll") for (int ni_ = 0; ni_ < 2; ++ni_)                    \
          acc[(MH)*4+f_][(NH)*2+ni_] = __builtin_amdgcn_mfma_f32_16x16x32_bf16(\
              bf_[ni_][ks_], af_[f_][ks_], acc[(MH)*4+f_][(NH)*2+ni_], 0,0,0); \
    __builtin_amdgcn_s_setprio(0);                                             \
    asm volatile("s_barrier" ::: "memory");                                    \
  }

template<int ACT, int OUTF, int KDIM>
__global__ __launch_bounds__(512, 2) void k_gemm(const __hip_bfloat16* __restrict__ A,
                                                 const __hip_bfloat16* __restrict__ Bt,
                                                 const float* __restrict__ bias,
                                                 void* __restrict__ Cout,
                                                 int M, int N) {
  extern __shared__ char lds[];
  constexpr int NKT = KDIM / 64;
  int tid = threadIdx.x;
  int w = tid >> 6, l = tid & 63;
  int wr = w >> 2, wc = w & 3;
  int ml = l & 15, quad = l >> 4;
  int n0 = blockIdx.x * 256, m0 = blockIdx.y * 256;

  const short* Ag = (const short*)A + (size_t)m0 * KDIM;
  const short* Bg = (const short*)Bt + (size_t)n0 * KDIM;

  // stage geometry: lane covers LDS row srow(+64 for 2nd call), slot l&7;
  // source slot pre-swizzled: (l&7) ^ (row&7) where row&7 = (l>>3)&7.
  int srow = w*8 + (l >> 3);
  int scol = (((l & 7) ^ ((l >> 3) & 7)) * 8);   // bf16 col within 64-k tile

  auto STAGE_HALF = [&](int n) {
    if (n >= 4*NKT) return;
    int kt = n >> 2;
    int isB = n & 1, h = (n >> 1) & 1, buf = kt & 1;
    const short* src = isB ? Bg : Ag;
    const short* g0 = src + (size_t)(h*128 + srow) * KDIM + kt*64 + scol;
    char* dst = lds + isB*65536 + (buf*2 + h)*16384 + w*1024;   // wave-uniform
    async16(g0, dst);
    async16(g0 + (size_t)64 * KDIM, dst + 8192);
  };

  // ds_read offsets (relative to half-base), swizzled: slot ^= row&7
  int aoffs[4][2], boffs[2][2];
#pragma unroll
  for (int f = 0; f < 4; ++f) {
    int r = wr*64 + f*16 + ml;
#pragma unroll
    for (int ks = 0; ks < 2; ++ks)
      aoffs[f][ks] = (r*128 + ks*64 + quad*16) ^ ((ml & 7) << 4);
  }
#pragma unroll
  for (int ni = 0; ni < 2; ++ni) {
    int rb = wc*32 + ni*16 + ml;
#pragma unroll
    for (int ks = 0; ks < 2; ++ks)
      boffs[ni][ks] = (rb*128 + ks*64 + quad*16) ^ ((ml & 7) << 4);
  }

  f32x4 acc[8][4];
#pragma unroll
  for (int i = 0; i < 8; ++i)
#pragma unroll
    for (int j = 0; j < 4; ++j) acc[i][j] = {0.f, 0.f, 0.f, 0.f};

  // prologue: stage KT0 (4 halves) + KT1 A0,B0; retire KT0; barrier.
#pragma unroll
  for (int n = 0; n < 6; ++n) STAGE_HALF(n);
  asm volatile("s_waitcnt vmcnt(4)" ::: "memory");
  asm volatile("s_barrier" ::: "memory");

  for (int cc = 0; cc < NKT/2; ++cc) {
    int g0 = cc * 8;
    PHASE(0, 0, 0, g0+0, 0)
    PHASE(0, 0, 1, g0+1, 0)
    PHASE(0, 1, 0, g0+2, 0)
    PHASE(0, 1, 1, g0+3, 1)
    PHASE(1, 0, 0, g0+4, 0)
    PHASE(1, 0, 1, g0+5, 0)
    PHASE(1, 1, 0, g0+6, 0)
    PHASE(1, 1, 1, g0+7, 1)
  }

  // ---- epilogue: lane owns 4 consecutive cols per frag (operand swap) ----
#pragma unroll
  for (int mi = 0; mi < 8; ++mi) {
    size_t row = (size_t)(m0 + (mi>>2)*128 + wr*64 + (mi&3)*16 + ml);
#pragma unroll
    for (int nj = 0; nj < 4; ++nj) {
      int col = n0 + (nj>>1)*128 + wc*32 + (nj&1)*16 + quad*4;
      f32x4 bj = *(const f32x4*)&bias[col];
      f32x4 v = acc[mi][nj] + bj;
      if (ACT == 1) {
#pragma unroll
        for (int e = 0; e < 4; ++e) v[e] = (v[e] > 0.0f) ? v[e] + 1.0f : __expf(v[e]);
      } else if (ACT == 2) {
#pragma unroll
        for (int e = 0; e < 4; ++e) {
          float vv = v[e], v2 = vv * vv;
          float ex = __expf(vv * fmaf(v2, -0.0713548327f, -1.5957691216f));
          v[e] = vv * __builtin_amdgcn_rcpf(1.0f + ex);   // inf-safe
        }
      }
      if (OUTF) {
        *(f32x4*)&((float*)Cout)[row * N + col] = v;
      } else {
        s16x4 sv;
#pragma unroll
        for (int e = 0; e < 4; ++e) {
          __hip_bfloat16 b = __float2bfloat16(v[e]);
          sv[e] = *(short*)&b;
        }
        *(s16x4*)&((__hip_bfloat16*)Cout)[row * N + col] = sv;
      }
    }
  }
}

// ---------- kv + ksum per (b,j,h), fp32 accumulate from bf16 ----------
__global__ __launch_bounds__(256) void k_kv(const __hip_bfloat16* __restrict__ pk,
                                            const __hip_bfloat16* __restrict__ v,
                                            float* __restrict__ kv,
                                            float* __restrict__ ksum) {
  __shared__ float spk[8][DH_];
  __shared__ float sv[8][DH_];
  int blk = blockIdx.x;          // (b*J + j)*H + h
  int h = blk & 7;
  int bj = blk >> 3;
  int j = bj % J_;
  int b = bj / J_;
  int tid = threadIdx.x;
  int tt = tid >> 5, dl = tid & 31;
  int dd = tid & 31, k0 = tid >> 5;
  float acc[4] = {0.f, 0.f, 0.f, 0.f};
  float ks = 0.f;
  for (int t0 = 0; t0 < T_; t0 += 8) {
    size_t row = (size_t)(b * T_ + t0 + tt) * J_ + j;
    spk[tt][dl] = __bfloat162float(pk[row * D_ + h * DH_ + dl]);
    sv[tt][dl]  = __bfloat162float(v [row * D_ + h * DH_ + dl]);
    __syncthreads();
#pragma unroll
    for (int q = 0; q < 8; ++q) {
      float vv = sv[q][dd];
#pragma unroll
      for (int m = 0; m < 4; ++m)
        acc[m] = fmaf(spk[q][k0 + (m << 3)], vv, acc[m]);
    }
    if (tid < 32) {
#pragma unroll
      for (int q = 0; q < 8; ++q) ks += spk[q][tid];
    }
    __syncthreads();
  }
#pragma unroll
  for (int m = 0; m < 4; ++m)
    kv[(size_t)blk * (DH_*DH_) + (size_t)(k0 + (m << 3)) * DH_ + dd] = acc[m];
  if (tid < 32) ksum[(size_t)blk * DH_ + tid] = ks;
}

// ---------- attn = (pq @ kv) / (pq @ ksum + eps) -> bf16 ----------
__global__ __launch_bounds__(256) void k_attn(const __hip_bfloat16* __restrict__ pq,
                                              const float* __restrict__ kv,
                                              const float* __restrict__ ksum,
                                              __hip_bfloat16* __restrict__ attn) {
  __shared__ float psf[32][264];
  __shared__ float dens[32][8];
  int bj = blockIdx.y;           // b*J + j
  int b = bj / J_, j = bj % J_;
  int t0 = blockIdx.x * 32;
  int tid = threadIdx.x, w = tid >> 6, l = tid & 63;
  int h = w*2 + (l >> 5), dd = l & 31;

  const float* kvp = kv + ((size_t)bj * 8 + h) * (DH_*DH_);
  float kvreg[32];
#pragma unroll
  for (int k = 0; k < 32; ++k) kvreg[k] = kvp[k*32 + dd];

  for (int tr = 0; tr < 32; ++tr) {
    int g = (b * T_ + t0 + tr) * J_ + j;
    psf[tr][tid] = __bfloat162float(pq[(size_t)g * D_ + tid]);
  }
  __syncthreads();

  {
    int tr = tid & 31, hh = tid >> 5;
    const float* ksp = ksum + ((size_t)bj * 8 + hh) * DH_;
    float dsum = 0.f;
#pragma unroll
    for (int k = 0; k < 32; ++k) dsum = fmaf(psf[tr][hh*32 + k], ksp[k], dsum);
    dens[tr][hh] = dsum;
  }
  __syncthreads();

  for (int tr = 0; tr < 32; ++tr) {
    const float* pr = &psf[tr][h*32];
    float num = 0.f;
#pragma unroll
    for (int k = 0; k < 32; ++k) num = fmaf(pr[k], kvreg[k], num);
    int g = (b * T_ + t0 + tr) * J_ + j;
    float rden = __builtin_amdgcn_rcpf(dens[tr][h] + EPSF);
    attn[(size_t)g * D_ + tid] = __float2bfloat16(num * rden);
  }
}

// ---------- u2 = LN(xs + sinh(|o|)/|o| * o)  (wave-per-row) ----------
__global__ __launch_bounds__(256) void k_u2(const __hip_bfloat16* __restrict__ o,
                                            const float* __restrict__ x,
                                            const float* __restrict__ g2,
                                            const float* __restrict__ beta2,
                                            __hip_bfloat16* __restrict__ u2) {
  int r = blockIdx.x * 4 + (threadIdx.x >> 6);
  int l = threadIdx.x & 63;
  const float* xr = x + (size_t)r * NP1;
  float ov[4], xs[4];
#pragma unroll
  for (int i = 0; i < 4; ++i) {
    ov[i] = __bfloat162float(o[(size_t)r * D_ + l + 64*i]);
    xs[i] = xr[1 + l + 64*i];
  }
  float p2 = ov[0]*ov[0]+ov[1]*ov[1]+ov[2]*ov[2]+ov[3]*ov[3];
  float s2o = wave_sum(p2);
  float no = fmaxf(sqrtf(s2o), EPSF);
  float e = __expf(no);
  float c = (e - 1.0f/e) * 0.5f / no;      // sinh(no)/no
  float mi[4];
#pragma unroll
  for (int i = 0; i < 4; ++i) mi[i] = xs[i] + c * ov[i];
  float q1 = mi[0]+mi[1]+mi[2]+mi[3];
  float q2 = mi[0]*mi[0]+mi[1]*mi[1]+mi[2]*mi[2]+mi[3]*mi[3];
  float s1 = wave_sum(q1);
  float s2 = wave_sum(q2);
  float mean = s1 * (1.0f/256.0f);
  float var = s2 * (1.0f/256.0f) - mean*mean;
  float rstd = rsqrtf(var + 1e-5f);
#pragma unroll
  for (int i = 0; i < 4; ++i) {
    int cc = l + 64*i;
    u2[(size_t)r * D_ + cc] = __float2bfloat16((mi[i]-mean)*rstd*g2[cc] + beta2[cc]);
  }
}

// ---------- out = expmap0(f), f fp32  (wave-per-row) ----------
__global__ __launch_bounds__(256) void k_out(const float* __restrict__ f,
                                             float* __restrict__ out) {
  int r = blockIdx.x * 4 + (threadIdx.x >> 6);
  int l = threadIdx.x & 63;
  const float* fr = f + (size_t)r * D_;
  float fv[4];
#pragma unroll
  for (int i = 0; i < 4; ++i) fv[i] = fr[l + 64*i];
  float p2 = fv[0]*fv[0]+fv[1]*fv[1]+fv[2]*fv[2]+fv[3]*fv[3];
  float s2 = wave_sum(p2);
  float n = fmaxf(sqrtf(s2), EPSF);
  float e = __expf(n);
  float ie = 1.0f / e;
  float sh = (e - ie) * 0.5f;
  float ch = (e + ie) * 0.5f;
  float s = sh / n;
  float* orow = out + (size_t)r * NP1;
  if (l == 0) orow[0] = ch;
#pragma unroll
  for (int i = 0; i < 4; ++i) orow[1 + l + 64*i] = s * fv[i];
}

extern "C" void kernel_launch(void* const* d_in, const int* in_sizes, int n_in,
                              void* d_out, int out_size, void* d_ws, size_t ws_size,
                              hipStream_t stream) {
  const float* x     = (const float*)d_in[0];
  const float* g1    = (const float*)d_in[1];
  const float* beta1 = (const float*)d_in[2];
  const float* Wq    = (const float*)d_in[3];
  const float* Wk    = (const float*)d_in[4];
  const float* Wv    = (const float*)d_in[5];
  const float* Wo    = (const float*)d_in[6];
  const float* bq    = (const float*)d_in[7];
  const float* bk    = (const float*)d_in[8];
  const float* bv    = (const float*)d_in[9];
  const float* bo    = (const float*)d_in[10];
  const float* g2    = (const float*)d_in[11];
  const float* beta2 = (const float*)d_in[12];
  const float* W1    = (const float*)d_in[13];
  const float* bf1   = (const float*)d_in[14];
  const float* W2    = (const float*)d_in[15];
  const float* bf2   = (const float*)d_in[16];
  float* out = (float*)d_out;
  char* ws = (char*)d_ws;

  // ---- workspace layout (bytes) ----
  size_t off = 0;
  __hip_bfloat16* wqT = (__hip_bfloat16*)(ws + off); off += (size_t)D_*D_*2;
  __hip_bfloat16* wkT = (__hip_bfloat16*)(ws + off); off += (size_t)D_*D_*2;
  __hip_bfloat16* wvT = (__hip_bfloat16*)(ws + off); off += (size_t)D_*D_*2;
  __hip_bfloat16* woT = (__hip_bfloat16*)(ws + off); off += (size_t)D_*D_*2;
  __hip_bfloat16* w1T = (__hip_bfloat16*)(ws + off); off += (size_t)HID_*D_*2;
  __hip_bfloat16* w2T = (__hip_bfloat16*)(ws + off); off += (size_t)D_*HID_*2;
  float* kvb = (float*)(ws + off); off += (size_t)(B_*J_*H_)*(DH_*DH_)*4;
  float* ksb = (float*)(ws + off); off += (size_t)(B_*J_*H_)*DH_*4;
  off = (off + 255) & ~(size_t)255;
  __hip_bfloat16* tb = (__hip_bfloat16*)(ws + off); off += (size_t)R_*D_*2;
  __hip_bfloat16* qb = (__hip_bfloat16*)(ws + off); off += (size_t)R_*D_*2;
  __hip_bfloat16* kb = (__hip_bfloat16*)(ws + off); off += (size_t)R_*D_*2;
  __hip_bfloat16* vb = (__hip_bfloat16*)(ws + off); off += (size_t)R_*D_*2;
  __hip_bfloat16* hid = (__hip_bfloat16*)(ws + off); off += (size_t)(R_/2)*HID_*2;
  float* fbuf = (float*)qb;   // fp32 R*256 aliases qb+kb (both consumed by then)

  // one-time: allow 128KB dynamic LDS on the GEMM instantiations
  static bool attr_done = false;
  if (!attr_done) {
    hipFuncSetAttribute((const void*)k_gemm<1,0,256>,  hipFuncAttributeMaxDynamicSharedMemorySize, 131072);
    hipFuncSetAttribute((const void*)k_gemm<0,0,256>,  hipFuncAttributeMaxDynamicSharedMemorySize, 131072);
    hipFuncSetAttribute((const void*)k_gemm<2,0,256>,  hipFuncAttributeMaxDynamicSharedMemorySize, 131072);
    hipFuncSetAttribute((const void*)k_gemm<0,1,1024>, hipFuncAttributeMaxDynamicSharedMemorySize, 131072);
    attr_done = true;
  }

  dim3 tconv(32, 8);
  k_wconv<<<dim3(D_/32,  D_/32),  tconv, 0, stream>>>(Wq, wqT, D_,  D_);
  k_wconv<<<dim3(D_/32,  D_/32),  tconv, 0, stream>>>(Wk, wkT, D_,  D_);
  k_wconv<<<dim3(D_/32,  D_/32),  tconv, 0, stream>>>(Wv, wvT, D_,  D_);
  k_wconv<<<dim3(D_/32,  D_/32),  tconv, 0, stream>>>(Wo, woT, D_,  D_);
  k_wconv<<<dim3(HID_/32, D_/32), tconv, 0, stream>>>(W1, w1T, D_,  HID_);
  k_wconv<<<dim3(D_/32, HID_/32), tconv, 0, stream>>>(W2, w2T, HID_, D_);

  k_t<<<R_/4, 256, 0, stream>>>(x, g1, beta1, tb);

  dim3 gqkv(D_/256, R_/256);                 // (1, 416)
  k_gemm<1,0,256><<<gqkv, 512, 131072, stream>>>(tb, wqT, bq, qb, R_, D_);
  k_gemm<1,0,256><<<gqkv, 512, 131072, stream>>>(tb, wkT, bk, kb, R_, D_);
  k_gemm<0,0,256><<<gqkv, 512, 131072, stream>>>(tb, wvT, bv, vb, R_, D_);

  k_kv<<<B_*J_*H_, 256, 0, stream>>>(kb, vb, kvb, ksb);
  k_attn<<<dim3(T_/32, B_*J_), 256, 0, stream>>>(qb, kvb, ksb, kb);   // attn -> kb

  k_gemm<0,0,256><<<gqkv, 512, 131072, stream>>>(kb, woT, bo, vb, R_, D_);  // o -> vb
  k_u2<<<R_/4, 256, 0, stream>>>(vb, x, g2, beta2, tb);                     // u2 -> tb

  const int Rc = R_ / 2;                     // 53248 rows per MLP chunk
  for (int c = 0; c < 2; ++c) {
    k_gemm<2,0,256><<<dim3(HID_/256, Rc/256), 512, 131072, stream>>>(
        tb + (size_t)c * Rc * D_, w1T, bf1, hid, Rc, HID_);
    k_gemm<0,1,1024><<<dim3(D_/256, Rc/256), 512, 131072, stream>>>(
        hid, w2T, bf2, fbuf + (size_t)c * Rc * D_, Rc, D_);
  }

  k_out<<<R_/4, 256, 0, stream>>>(fbuf, out);
}